// Round 1
// baseline (497.133 us; speedup 1.0000x reference)
//
#include <hip/hip_runtime.h>
#include <math.h>

#define NRAYS 32768
#define NMULTI 6

__device__ __forceinline__ float sigmoidf_(float v) { return 1.0f / (1.0f + expf(-v)); }

// ---------------------------------------------------------------------------
// Kernel A: contraction + hash-grid encode + erf-weighted mean over samples
// block = 384 threads = 6 waves; wave j handles sample j of 64 rays
// ---------------------------------------------------------------------------
__global__ __launch_bounds__(384) void enc_kernel(
    const float* __restrict__ means, const float* __restrict__ stds,
    const float* __restrict__ emb, float* __restrict__ features)
{
    __shared__ float fsum[64][40];
    const int tid  = threadIdx.x;
    const int lane = tid & 63;
    const int j    = tid >> 6;          // sample index 0..5
    const int ray  = blockIdx.x * 64 + lane;

    for (int i = tid; i < 64 * 40; i += 384) (&fsum[0][0])[i] = 0.0f;
    __syncthreads();

    const int p = ray * NMULTI + j;
    const float mx = means[p * 3 + 0], my = means[p * 3 + 1], mz = means[p * 3 + 2];
    const float sd = stds[p];

    // mipnerf360 contraction + std scaling
    float r2 = fmaxf(mx * mx + my * my + mz * mz, 1.1920929e-07f);
    float rr = sqrtf(r2);
    float zx, zy, zz, s;
    if (r2 <= 1.0f) { zx = mx; zy = my; zz = mz; s = sd; }
    else {
        float sc = (2.0f * rr - 1.0f) / r2;
        zx = mx * sc; zy = my * sc; zz = mz * sc;
        float det = (1.0f / r2) * sc * sc;
        s = sd * cbrtf(det);
    }
    zx *= 0.5f; zy *= 0.5f; zz *= 0.5f; s *= 0.5f;   // bound = 2
    const float ux = fminf(fmaxf((zx + 1.0f) * 0.5f, 0.0f), 1.0f);
    const float uy = fminf(fmaxf((zy + 1.0f) * 0.5f, 0.0f), 1.0f);
    const float uz = fminf(fmaxf((zz + 1.0f) * 0.5f, 0.0f), 1.0f);

    const float4* __restrict__ etab = (const float4*)emb;

    constexpr int RES[10] = {16, 32, 64, 128, 256, 512, 1024, 2048, 4096, 8192};
    constexpr int OFF[10] = {0, 4920, 40864, 315496, 2412648, 4509800,
                             6606952, 8704104, 10801256, 12898408};

    #pragma unroll
    for (int l = 0; l < 10; ++l) {
        const float Rf = (float)RES[l];
        const float wl = erff(1.0f / fmaxf(2.8284271247461903f * s * Rf, 1e-10f));

        float px = ux * (Rf - 1.0f) + 0.5f;
        float py = uy * (Rf - 1.0f) + 0.5f;
        float pz = uz * (Rf - 1.0f) + 0.5f;
        float fpx = floorf(px), fpy = floorf(py), fpz = floorf(pz);
        float fx = px - fpx, fy = py - fpy, fz = pz - fpz;
        unsigned ix = (unsigned)fpx, iy = (unsigned)fpy, iz = (unsigned)fpz;

        float wx[2] = {1.0f - fx, fx};
        float wy[2] = {1.0f - fy, fy};
        float wz[2] = {1.0f - fz, fz};
        unsigned ox[2], oy[2], oz[2];
        if (l < 3) {                       // dense levels
            unsigned S = (unsigned)RES[l] + 1u;
            ox[0] = ix;          ox[1] = ix + 1u;
            oy[0] = iy * S;      oy[1] = oy[0] + S;
            oz[0] = iz * S * S;  oz[1] = oz[0] + S * S;
        } else {                           // hashed levels, params = 2^21
            ox[0] = ix;                    ox[1] = ix + 1u;
            oy[0] = iy * 2654435761u;      oy[1] = oy[0] + 2654435761u;
            oz[0] = iz * 805459861u;       oz[1] = oz[0] + 805459861u;
        }

        float ax = 0.f, ay = 0.f, az = 0.f, aw = 0.f;
        #pragma unroll
        for (int c = 0; c < 8; ++c) {
            const int bx = (c >> 2) & 1, by = (c >> 1) & 1, bz = c & 1;
            unsigned idx;
            if (l < 3) idx = ox[bx] + oy[by] + oz[bz];
            else       idx = (ox[bx] ^ oy[by] ^ oz[bz]) & 0x1FFFFFu;
            const float w = wx[bx] * wy[by] * wz[bz];
            const float4 e = etab[OFF[l] + (int)idx];
            ax += w * e.x; ay += w * e.y; az += w * e.z; aw += w * e.w;
        }
        atomicAdd(&fsum[lane][l * 4 + 0], ax * wl);
        atomicAdd(&fsum[lane][l * 4 + 1], ay * wl);
        atomicAdd(&fsum[lane][l * 4 + 2], az * wl);
        atomicAdd(&fsum[lane][l * 4 + 3], aw * wl);
    }
    __syncthreads();

    const float inv6 = 1.0f / 6.0f;
    for (int i = tid; i < 64 * 40; i += 384)
        features[blockIdx.x * 64 * 40 + i] = (&fsum[0][0])[i] * inv6;
}

// ---------------------------------------------------------------------------
// Kernel B: density MLP  features[64rays,40] -> h0[64] -> x[256]; density out
// ---------------------------------------------------------------------------
__global__ __launch_bounds__(256) void dens_kernel(
    const float* __restrict__ features,
    const float* __restrict__ dw0, const float* __restrict__ db0,
    const float* __restrict__ dw1, const float* __restrict__ db1,
    float* __restrict__ x_out, float* __restrict__ dens_out)
{
    __shared__ __align__(16) float feat_s[64][40];
    __shared__ __align__(16) float h0_s[64][64];
    const int tid  = threadIdx.x;
    const int ray0 = blockIdx.x * 64;

    for (int i = tid; i < 64 * 40; i += 256)
        (&feat_s[0][0])[i] = features[ray0 * 40 + i];
    __syncthreads();

    {   // layer 0: 40 -> 64, relu
        const int nn = tid & 63;
        const int q  = tid >> 6;          // 4 groups x 16 rays
        float wk[40];
        #pragma unroll
        for (int k = 0; k < 40; ++k) wk[k] = dw0[k * 64 + nn];
        const float b = db0[nn];
        #pragma unroll 2
        for (int r = q * 16; r < q * 16 + 16; ++r) {
            float acc = b;
            #pragma unroll
            for (int k = 0; k < 40; ++k) acc += wk[k] * feat_s[r][k];
            h0_s[r][nn] = fmaxf(acc, 0.0f);
        }
    }
    __syncthreads();

    {   // layer 1: 64 -> 256 (linear); density = softplus(x0 - 1)
        const int nn = tid;
        float wk[64];
        #pragma unroll
        for (int k = 0; k < 64; ++k) wk[k] = dw1[k * 256 + nn];
        const float b = db1[nn];
        #pragma unroll 2
        for (int r = 0; r < 64; ++r) {
            float acc = b;
            #pragma unroll
            for (int k = 0; k < 64; ++k) acc += wk[k] * h0_s[r][k];
            x_out[(ray0 + r) * 256 + nn] = acc;
            if (nn == 0) {
                float z = acc - 1.0f;   // DENSITY_BIAS
                dens_out[ray0 + r] = fmaxf(z, 0.0f) + log1pf(expf(-fabsf(z)));
            }
        }
    }
}

// ---------------------------------------------------------------------------
// Kernel C: rgb branch. 16 rays/block, 256 threads (thread = output neuron)
// inp[283] = [x(256), dir_enc(27)]; y1 = relu(inp@sw0); y2 = relu([y1,inp]@sw1)
// rgb = sigmoid(y2@rw + rb) * 1.002 - 0.001
// ---------------------------------------------------------------------------
__global__ __launch_bounds__(256) void rgb_kernel(
    const float* __restrict__ x_in, const float* __restrict__ viewdirs,
    const float* __restrict__ sw0, const float* __restrict__ sb0,
    const float* __restrict__ sw1, const float* __restrict__ sb1,
    const float* __restrict__ rw,  const float* __restrict__ rb,
    float* __restrict__ out)
{
    __shared__ __align__(16) float inp_s[16][284];
    __shared__ __align__(16) float y1_s[16][256];
    __shared__ __align__(16) float y2_s[16][256];
    const int tid  = threadIdx.x;
    const int ray0 = blockIdx.x * 16;

    for (int i = tid; i < 16 * 256; i += 256) {
        int r = i >> 8, k = i & 255;
        inp_s[r][k] = x_in[(ray0 + r) * 256 + k];
    }
    // dir_enc: [vd(3), sin(12), cos(12)], + zero pad at 283
    for (int i = tid; i < 16 * 28; i += 256) {
        int r = i / 28, q = i % 28;
        const float* vd = &viewdirs[(size_t)(ray0 + r) * 3];
        float v;
        if (q < 3)       v = vd[q];
        else if (q < 15) { int ii = q - 3;  v = sinf(vd[ii % 3] * (float)(1 << (ii / 3))); }
        else if (q < 27) { int ii = q - 15; v = cosf(vd[ii % 3] * (float)(1 << (ii / 3))); }
        else             v = 0.0f;
        inp_s[r][256 + q] = v;
    }
    __syncthreads();

    const int nn = tid;
    float acc[16];

    {   // G2: 283 -> 256, relu
        const float b = sb0[nn];
        #pragma unroll
        for (int r = 0; r < 16; ++r) acc[r] = b;
        for (int k4 = 0; k4 < 70; ++k4) {
            const int k = k4 * 4;
            const float w0 = sw0[(k + 0) * 256 + nn];
            const float w1 = sw0[(k + 1) * 256 + nn];
            const float w2 = sw0[(k + 2) * 256 + nn];
            const float w3 = sw0[(k + 3) * 256 + nn];
            #pragma unroll
            for (int r = 0; r < 16; ++r) {
                const float4 v = *reinterpret_cast<const float4*>(&inp_s[r][k]);
                acc[r] += w0 * v.x + w1 * v.y + w2 * v.z + w3 * v.w;
            }
        }
        #pragma unroll
        for (int k = 280; k < 283; ++k) {
            const float w = sw0[k * 256 + nn];
            #pragma unroll
            for (int r = 0; r < 16; ++r) acc[r] += w * inp_s[r][k];
        }
        #pragma unroll
        for (int r = 0; r < 16; ++r) y1_s[r][nn] = fmaxf(acc[r], 0.0f);
    }
    __syncthreads();

    {   // G3: [y1(256), inp(283)] -> 256, relu
        const float b = sb1[nn];
        #pragma unroll
        for (int r = 0; r < 16; ++r) acc[r] = b;
        for (int k4 = 0; k4 < 64; ++k4) {          // y1 part
            const int k = k4 * 4;
            const float w0 = sw1[(k + 0) * 256 + nn];
            const float w1 = sw1[(k + 1) * 256 + nn];
            const float w2 = sw1[(k + 2) * 256 + nn];
            const float w3 = sw1[(k + 3) * 256 + nn];
            #pragma unroll
            for (int r = 0; r < 16; ++r) {
                const float4 v = *reinterpret_cast<const float4*>(&y1_s[r][k]);
                acc[r] += w0 * v.x + w1 * v.y + w2 * v.z + w3 * v.w;
            }
        }
        for (int k4 = 0; k4 < 70; ++k4) {          // inp part (weight rows 256+)
            const int k = k4 * 4;
            const float w0 = sw1[(256 + k + 0) * 256 + nn];
            const float w1 = sw1[(256 + k + 1) * 256 + nn];
            const float w2 = sw1[(256 + k + 2) * 256 + nn];
            const float w3 = sw1[(256 + k + 3) * 256 + nn];
            #pragma unroll
            for (int r = 0; r < 16; ++r) {
                const float4 v = *reinterpret_cast<const float4*>(&inp_s[r][k]);
                acc[r] += w0 * v.x + w1 * v.y + w2 * v.z + w3 * v.w;
            }
        }
        #pragma unroll
        for (int k = 280; k < 283; ++k) {
            const float w = sw1[(256 + k) * 256 + nn];
            #pragma unroll
            for (int r = 0; r < 16; ++r) acc[r] += w * inp_s[r][k];
        }
        #pragma unroll
        for (int r = 0; r < 16; ++r) y2_s[r][nn] = fmaxf(acc[r], 0.0f);
    }
    __syncthreads();

    {   // G4: 256 -> 3, sigmoid; 16 threads per ray, shfl-reduce
        const int r = tid >> 4, l16 = tid & 15;
        float a0 = 0.f, a1 = 0.f, a2 = 0.f;
        for (int k = l16; k < 256; k += 16) {
            const float v = y2_s[r][k];
            a0 += v * rw[k * 3 + 0];
            a1 += v * rw[k * 3 + 1];
            a2 += v * rw[k * 3 + 2];
        }
        #pragma unroll
        for (int m = 8; m >= 1; m >>= 1) {
            a0 += __shfl_xor(a0, m, 16);
            a1 += __shfl_xor(a1, m, 16);
            a2 += __shfl_xor(a2, m, 16);
        }
        if (l16 == 0) {
            const int rr = ray0 + r;
            out[NRAYS + rr * 3 + 0] = sigmoidf_(a0 + rb[0]) * 1.002f - 0.001f;
            out[NRAYS + rr * 3 + 1] = sigmoidf_(a1 + rb[1]) * 1.002f - 0.001f;
            out[NRAYS + rr * 3 + 2] = sigmoidf_(a2 + rb[2]) * 1.002f - 0.001f;
        }
    }
}

// ---------------------------------------------------------------------------
extern "C" void kernel_launch(void* const* d_in, const int* in_sizes, int n_in,
                              void* d_out, int out_size, void* d_ws, size_t ws_size,
                              hipStream_t stream)
{
    const float* means    = (const float*)d_in[0];
    const float* stds     = (const float*)d_in[1];
    const float* viewdirs = (const float*)d_in[2];
    const float* emb      = (const float*)d_in[3];
    const float* dw0      = (const float*)d_in[4];
    const float* db0      = (const float*)d_in[5];
    const float* dw1      = (const float*)d_in[6];
    const float* db1      = (const float*)d_in[7];
    const float* sw0      = (const float*)d_in[8];
    const float* sb0      = (const float*)d_in[9];
    const float* sw1      = (const float*)d_in[10];
    const float* sb1      = (const float*)d_in[11];
    const float* rw       = (const float*)d_in[12];
    const float* rb       = (const float*)d_in[13];

    float* out      = (float*)d_out;
    float* ws       = (float*)d_ws;
    float* features = ws;                       // 32768*40  f32 (5.2 MB)
    float* x        = ws + (size_t)NRAYS * 40;  // 32768*256 f32 (33.6 MB)

    enc_kernel <<<NRAYS / 64, 384, 0, stream>>>(means, stds, emb, features);
    dens_kernel<<<NRAYS / 64, 256, 0, stream>>>(features, dw0, db0, dw1, db1, x, out);
    rgb_kernel <<<NRAYS / 16, 256, 0, stream>>>(x, viewdirs, sw0, sb0, sw1, sb1, rw, rb, out);
}

// Round 2
// 255.539 us; speedup vs baseline: 1.9454x; 1.9454x over previous
//
#include <hip/hip_runtime.h>
#include <hip/hip_bf16.h>
#include <math.h>

#define NRAYS 32768
#define NMULTI 6

typedef __attribute__((ext_vector_type(8))) short short8v;
typedef __attribute__((ext_vector_type(4))) float float4v;

__device__ __forceinline__ float sigmoidf_(float v) { return 1.0f / (1.0f + expf(-v)); }
__device__ __forceinline__ short f2bf(float v) {
    __hip_bfloat16 b = __float2bfloat16(v);
    return *reinterpret_cast<short*>(&b);
}

// ---------------------------------------------------------------------------
// Pack f32 weights [K x 256] into MFMA B-fragment-major bf16:
// dst[((ks*16+nt)*64+lane)*8+e] = W[ks*32+(lane>>4)*8+e][nt*16+(lane&15)], 0-pad k>=K
// ---------------------------------------------------------------------------
__global__ void pack_w(const float* __restrict__ src, short* __restrict__ dst,
                       int K, int total)
{
    int o = blockIdx.x * 256 + threadIdx.x;
    if (o >= total) return;
    int e = o & 7, lane = (o >> 3) & 63, nt = (o >> 9) & 15, ks = o >> 13;
    int k = ks * 32 + ((lane >> 4) << 3) + e;
    int n = nt * 16 + (lane & 15);
    float v = (k < K) ? src[k * 256 + n] : 0.0f;
    dst[o] = f2bf(v);
}

// ---------------------------------------------------------------------------
// Kernel A: contraction + hash-grid encode + erf-weighted mean over samples
// ---------------------------------------------------------------------------
__global__ __launch_bounds__(384) void enc_kernel(
    const float* __restrict__ means, const float* __restrict__ stds,
    const float* __restrict__ emb, float* __restrict__ features)
{
    __shared__ float fsum[64][40];
    const int tid  = threadIdx.x;
    const int lane = tid & 63;
    const int j    = tid >> 6;          // sample index 0..5
    const int ray  = blockIdx.x * 64 + lane;

    for (int i = tid; i < 64 * 40; i += 384) (&fsum[0][0])[i] = 0.0f;
    __syncthreads();

    const int p = ray * NMULTI + j;
    const float mx = means[p * 3 + 0], my = means[p * 3 + 1], mz = means[p * 3 + 2];
    const float sd = stds[p];

    float r2 = fmaxf(mx * mx + my * my + mz * mz, 1.1920929e-07f);
    float rr = sqrtf(r2);
    float zx, zy, zz, s;
    if (r2 <= 1.0f) { zx = mx; zy = my; zz = mz; s = sd; }
    else {
        float sc = (2.0f * rr - 1.0f) / r2;
        zx = mx * sc; zy = my * sc; zz = mz * sc;
        float det = (1.0f / r2) * sc * sc;
        s = sd * cbrtf(det);
    }
    zx *= 0.5f; zy *= 0.5f; zz *= 0.5f; s *= 0.5f;   // bound = 2
    const float ux = fminf(fmaxf((zx + 1.0f) * 0.5f, 0.0f), 1.0f);
    const float uy = fminf(fmaxf((zy + 1.0f) * 0.5f, 0.0f), 1.0f);
    const float uz = fminf(fmaxf((zz + 1.0f) * 0.5f, 0.0f), 1.0f);

    const float4* __restrict__ etab = (const float4*)emb;

    constexpr int RES[10] = {16, 32, 64, 128, 256, 512, 1024, 2048, 4096, 8192};
    constexpr int OFF[10] = {0, 4920, 40864, 315496, 2412648, 4509800,
                             6606952, 8704104, 10801256, 12898408};

    #pragma unroll
    for (int l = 0; l < 10; ++l) {
        const float Rf = (float)RES[l];
        const float wl = erff(1.0f / fmaxf(2.8284271247461903f * s * Rf, 1e-10f));

        float px = ux * (Rf - 1.0f) + 0.5f;
        float py = uy * (Rf - 1.0f) + 0.5f;
        float pz = uz * (Rf - 1.0f) + 0.5f;
        float fpx = floorf(px), fpy = floorf(py), fpz = floorf(pz);
        float fx = px - fpx, fy = py - fpy, fz = pz - fpz;
        unsigned ix = (unsigned)fpx, iy = (unsigned)fpy, iz = (unsigned)fpz;

        float wx[2] = {1.0f - fx, fx};
        float wy[2] = {1.0f - fy, fy};
        float wz[2] = {1.0f - fz, fz};
        unsigned ox[2], oy[2], oz[2];
        if (l < 3) {
            unsigned S = (unsigned)RES[l] + 1u;
            ox[0] = ix;          ox[1] = ix + 1u;
            oy[0] = iy * S;      oy[1] = oy[0] + S;
            oz[0] = iz * S * S;  oz[1] = oz[0] + S * S;
        } else {
            ox[0] = ix;                    ox[1] = ix + 1u;
            oy[0] = iy * 2654435761u;      oy[1] = oy[0] + 2654435761u;
            oz[0] = iz * 805459861u;       oz[1] = oz[0] + 805459861u;
        }

        float ax = 0.f, ay = 0.f, az = 0.f, aw = 0.f;
        #pragma unroll
        for (int c = 0; c < 8; ++c) {
            const int bx = (c >> 2) & 1, by = (c >> 1) & 1, bz = c & 1;
            unsigned idx;
            if (l < 3) idx = ox[bx] + oy[by] + oz[bz];
            else       idx = (ox[bx] ^ oy[by] ^ oz[bz]) & 0x1FFFFFu;
            const float w = wx[bx] * wy[by] * wz[bz];
            const float4 e = etab[OFF[l] + (int)idx];
            ax += w * e.x; ay += w * e.y; az += w * e.z; aw += w * e.w;
        }
        atomicAdd(&fsum[lane][l * 4 + 0], ax * wl);
        atomicAdd(&fsum[lane][l * 4 + 1], ay * wl);
        atomicAdd(&fsum[lane][l * 4 + 2], az * wl);
        atomicAdd(&fsum[lane][l * 4 + 3], aw * wl);
    }
    __syncthreads();

    const float inv6 = 1.0f / 6.0f;
    for (int i = tid; i < 64 * 40; i += 384)
        features[blockIdx.x * 64 * 40 + i] = (&fsum[0][0])[i] * inv6;
}

// ---------------------------------------------------------------------------
// Kernel B: density MLP  features[64,40] -> h0[64] -> x[256] (bf16 out)
// ---------------------------------------------------------------------------
__global__ __launch_bounds__(256) void dens_kernel(
    const float* __restrict__ features,
    const float* __restrict__ dw0, const float* __restrict__ db0,
    const float* __restrict__ dw1, const float* __restrict__ db1,
    short* __restrict__ x_out, float* __restrict__ dens_out)
{
    __shared__ __align__(16) float feat_s[64][40];
    __shared__ __align__(16) float h0_s[64][64];
    const int tid  = threadIdx.x;
    const int ray0 = blockIdx.x * 64;

    for (int i = tid; i < 64 * 40; i += 256)
        (&feat_s[0][0])[i] = features[ray0 * 40 + i];
    __syncthreads();

    {   // layer 0: 40 -> 64, relu
        const int nn = tid & 63;
        const int q  = tid >> 6;
        float wk[40];
        #pragma unroll
        for (int k = 0; k < 40; ++k) wk[k] = dw0[k * 64 + nn];
        const float b = db0[nn];
        #pragma unroll 2
        for (int r = q * 16; r < q * 16 + 16; ++r) {
            float acc = b;
            #pragma unroll
            for (int k = 0; k < 40; ++k) acc += wk[k] * feat_s[r][k];
            h0_s[r][nn] = fmaxf(acc, 0.0f);
        }
    }
    __syncthreads();

    {   // layer 1: 64 -> 256; density = softplus(x0 - 1)
        const int nn = tid;
        float wk[64];
        #pragma unroll
        for (int k = 0; k < 64; ++k) wk[k] = dw1[k * 256 + nn];
        const float b = db1[nn];
        #pragma unroll 2
        for (int r = 0; r < 64; ++r) {
            float acc = b;
            #pragma unroll
            for (int k = 0; k < 64; ++k) acc += wk[k] * h0_s[r][k];
            x_out[(size_t)(ray0 + r) * 256 + nn] = f2bf(acc);
            if (nn == 0) {
                float z = acc - 1.0f;
                dens_out[ray0 + r] = fmaxf(z, 0.0f) + log1pf(expf(-fabsf(z)));
            }
        }
    }
}

// ---------------------------------------------------------------------------
// Kernel C: rgb branch via MFMA. 64 rays/block, 4 waves, wave = 16-ray m-tile.
// LDS row layout (bf16, stride 552): [y1(0..255) | x(256..511) | dir(512..538) | 0]
// ---------------------------------------------------------------------------
__global__ __launch_bounds__(256, 2) void rgb_mfma(
    const short* __restrict__ x_bf, const float* __restrict__ viewdirs,
    const short* __restrict__ w0p, const float* __restrict__ sb0,
    const short* __restrict__ w1p, const float* __restrict__ sb1,
    const float* __restrict__ rw,  const float* __restrict__ rb,
    float* __restrict__ out)
{
    __shared__ __align__(16) short inp_s[64][552];
    const int tid  = threadIdx.x;
    const int lane = tid & 63;
    const int wv   = tid >> 6;              // wave id = m-tile
    const int ray0 = blockIdx.x * 64;

    {   // x part -> cols 256..511 (short8 copies)
        const short8v* xg = (const short8v*)x_bf;
        for (int i = tid; i < 64 * 32; i += 256) {
            int r = i >> 5, c = i & 31;
            *(short8v*)&inp_s[r][256 + c * 8] = xg[(size_t)(ray0 + r) * 32 + c];
        }
    }
    for (int i = tid; i < 64 * 27; i += 256) {   // dir enc -> cols 512..538
        int r = i / 27, q = i % 27;
        const float* vd = &viewdirs[(size_t)(ray0 + r) * 3];
        float v;
        if (q < 3)       v = vd[q];
        else if (q < 15) { int ii = q - 3;  v = sinf(vd[ii % 3] * (float)(1 << (ii / 3))); }
        else             { int ii = q - 15; v = cosf(vd[ii % 3] * (float)(1 << (ii / 3))); }
        inp_s[r][512 + q] = f2bf(v);
    }
    for (int i = tid; i < 64 * 13; i += 256) {   // zero pad cols 539..551
        int r = i / 13, c = i % 13;
        inp_s[r][539 + c] = 0;
    }
    __syncthreads();

    const int arow  = wv * 16 + (lane & 15);
    const int kseg  = (lane >> 4) * 8;
    const int crow0 = wv * 16 + (lane >> 4) * 4;
    const int ccol  = lane & 15;
    const short8v* w0f = (const short8v*)w0p;
    const short8v* w1f = (const short8v*)w1p;

    float4v acc[16];

    // ---- GEMM1: y1 = relu(inp @ sw0 + sb0), K = 288 (9 k-steps)
    #pragma unroll
    for (int nt = 0; nt < 16; ++nt) acc[nt] = (float4v){0.f, 0.f, 0.f, 0.f};
    for (int ks = 0; ks < 9; ++ks) {
        short8v a = *(const short8v*)&inp_s[arow][256 + ks * 32 + kseg];
        #pragma unroll
        for (int nt = 0; nt < 16; ++nt) {
            short8v b = w0f[(ks * 16 + nt) * 64 + lane];
            acc[nt] = __builtin_amdgcn_mfma_f32_16x16x32_bf16(a, b, acc[nt], 0, 0, 0);
        }
    }
    #pragma unroll
    for (int nt = 0; nt < 16; ++nt) {
        float bias = sb0[nt * 16 + ccol];
        #pragma unroll
        for (int j = 0; j < 4; ++j)
            inp_s[crow0 + j][nt * 16 + ccol] = f2bf(fmaxf(acc[nt][j] + bias, 0.0f));
    }
    __syncthreads();

    // ---- GEMM2: y2 = relu([y1,x,dir] @ sw1 + sb1), K = 544 (17 k-steps)
    #pragma unroll
    for (int nt = 0; nt < 16; ++nt) acc[nt] = (float4v){0.f, 0.f, 0.f, 0.f};
    for (int ks = 0; ks < 17; ++ks) {
        short8v a = *(const short8v*)&inp_s[arow][ks * 32 + kseg];
        #pragma unroll
        for (int nt = 0; nt < 16; ++nt) {
            short8v b = w1f[(ks * 16 + nt) * 64 + lane];
            acc[nt] = __builtin_amdgcn_mfma_f32_16x16x32_bf16(a, b, acc[nt], 0, 0, 0);
        }
    }

    // ---- y2 = relu(acc + sb1) in regs; rgb = sigmoid(y2 @ rw + rb)
    float p[4][3];
    #pragma unroll
    for (int j = 0; j < 4; ++j) { p[j][0] = p[j][1] = p[j][2] = 0.f; }
    #pragma unroll
    for (int nt = 0; nt < 16; ++nt) {
        float bias = sb1[nt * 16 + ccol];
        const float* rwn = &rw[(size_t)(nt * 16 + ccol) * 3];
        float r0 = rwn[0], r1 = rwn[1], r2 = rwn[2];
        #pragma unroll
        for (int j = 0; j < 4; ++j) {
            float y = fmaxf(acc[nt][j] + bias, 0.0f);
            p[j][0] += y * r0; p[j][1] += y * r1; p[j][2] += y * r2;
        }
    }
    #pragma unroll
    for (int m = 1; m <= 8; m <<= 1) {
        #pragma unroll
        for (int j = 0; j < 4; ++j) {
            p[j][0] += __shfl_xor(p[j][0], m);
            p[j][1] += __shfl_xor(p[j][1], m);
            p[j][2] += __shfl_xor(p[j][2], m);
        }
    }
    if ((lane & 15) == 0) {
        #pragma unroll
        for (int j = 0; j < 4; ++j) {
            int ray = ray0 + crow0 + j;
            out[NRAYS + ray * 3 + 0] = sigmoidf_(p[j][0] + rb[0]) * 1.002f - 0.001f;
            out[NRAYS + ray * 3 + 1] = sigmoidf_(p[j][1] + rb[1]) * 1.002f - 0.001f;
            out[NRAYS + ray * 3 + 2] = sigmoidf_(p[j][2] + rb[2]) * 1.002f - 0.001f;
        }
    }
}

// ---------------------------------------------------------------------------
extern "C" void kernel_launch(void* const* d_in, const int* in_sizes, int n_in,
                              void* d_out, int out_size, void* d_ws, size_t ws_size,
                              hipStream_t stream)
{
    const float* means    = (const float*)d_in[0];
    const float* stds     = (const float*)d_in[1];
    const float* viewdirs = (const float*)d_in[2];
    const float* emb      = (const float*)d_in[3];
    const float* dw0      = (const float*)d_in[4];
    const float* db0      = (const float*)d_in[5];
    const float* dw1      = (const float*)d_in[6];
    const float* db1      = (const float*)d_in[7];
    const float* sw0      = (const float*)d_in[8];
    const float* sb0      = (const float*)d_in[9];
    const float* sw1      = (const float*)d_in[10];
    const float* sb1      = (const float*)d_in[11];
    const float* rw       = (const float*)d_in[12];
    const float* rb       = (const float*)d_in[13];

    float* out      = (float*)d_out;
    float* ws       = (float*)d_ws;
    float* features = ws;                                   // 32768*40 f32
    short* x_bf     = (short*)(ws + (size_t)NRAYS * 40);    // 32768*256 bf16
    short* w0p      = x_bf + (size_t)NRAYS * 256;           // 9*16*64*8
    short* w1p      = w0p + 9 * 16 * 64 * 8;                // 17*16*64*8

    pack_w<<<(9 * 16 * 64 * 8 + 255) / 256, 256, 0, stream>>>(sw0, w0p, 283, 9 * 16 * 64 * 8);
    pack_w<<<(17 * 16 * 64 * 8 + 255) / 256, 256, 0, stream>>>(sw1, w1p, 539, 17 * 16 * 64 * 8);
    enc_kernel <<<NRAYS / 64, 384, 0, stream>>>(means, stds, emb, features);
    dens_kernel<<<NRAYS / 64, 256, 0, stream>>>(features, dw0, db0, dw1, db1, x_bf, out);
    rgb_mfma   <<<NRAYS / 64, 256, 0, stream>>>(x_bf, viewdirs, w0p, sb0, w1p, sb1, rw, rb, out);
}

// Round 3
// 230.236 us; speedup vs baseline: 2.1592x; 1.1099x over previous
//
#include <hip/hip_runtime.h>
#include <hip/hip_bf16.h>
#include <math.h>

#define NRAYS 32768
#define NMULTI 6

typedef __attribute__((ext_vector_type(8))) short short8v;
typedef __attribute__((ext_vector_type(4))) float float4v;

__device__ __forceinline__ float sigmoidf_(float v) { return 1.0f / (1.0f + expf(-v)); }
__device__ __forceinline__ short f2bf(float v) {
    __hip_bfloat16 b = __float2bfloat16(v);
    return *reinterpret_cast<short*>(&b);
}

// ---------------------------------------------------------------------------
// Pack f32 weights [K x 256] into MFMA B-fragment-major bf16:
// dst[((ks*16+nt)*64+lane)*8+e] = W[ks*32+(lane>>4)*8+e][nt*16+(lane&15)], 0-pad k>=K
// ---------------------------------------------------------------------------
__global__ void pack_w(const float* __restrict__ src, short* __restrict__ dst,
                       int K, int total)
{
    int o = blockIdx.x * 256 + threadIdx.x;
    if (o >= total) return;
    int e = o & 7, lane = (o >> 3) & 63, nt = (o >> 9) & 15, ks = o >> 13;
    int k = ks * 32 + ((lane >> 4) << 3) + e;
    int n = nt * 16 + (lane & 15);
    float v = (k < K) ? src[k * 256 + n] : 0.0f;
    dst[o] = f2bf(v);
}

// ---------------------------------------------------------------------------
// Encode 5 levels starting at L0 (compile-time) for one point; atomicAdd into
// fsum[ray][ (L0+i)*4 + c ]. Skips levels whose erf weight is negligible.
// ---------------------------------------------------------------------------
template<int L0>
__device__ __forceinline__ void encode5(
    float ux, float uy, float uz, float s,
    const float4* __restrict__ etab, float (*fsum)[40], int ray_l)
{
    constexpr int RES[10] = {16, 32, 64, 128, 256, 512, 1024, 2048, 4096, 8192};
    constexpr int OFF[10] = {0, 4920, 40864, 315496, 2412648, 4509800,
                             6606952, 8704104, 10801256, 12898408};
    #pragma unroll
    for (int i = 0; i < 5; ++i) {
        const int l = L0 + i;
        const float Rf = (float)RES[l];
        const float wl = erff(1.0f / fmaxf(2.8284271247461903f * s * Rf, 1e-10f));
        if (wl < 0.01f) continue;     // contribution bound wl*0.1/6 < 1.7e-4

        float px = ux * (Rf - 1.0f) + 0.5f;
        float py = uy * (Rf - 1.0f) + 0.5f;
        float pz = uz * (Rf - 1.0f) + 0.5f;
        float fpx = floorf(px), fpy = floorf(py), fpz = floorf(pz);
        float fx = px - fpx, fy = py - fpy, fz = pz - fpz;
        unsigned ix = (unsigned)fpx, iy = (unsigned)fpy, iz = (unsigned)fpz;

        float wx[2] = {1.0f - fx, fx};
        float wy[2] = {1.0f - fy, fy};
        float wz[2] = {1.0f - fz, fz};
        unsigned ox[2], oy[2], oz[2];
        if (l < 3) {                       // dense levels
            unsigned S = (unsigned)RES[l] + 1u;
            ox[0] = ix;          ox[1] = ix + 1u;
            oy[0] = iy * S;      oy[1] = oy[0] + S;
            oz[0] = iz * S * S;  oz[1] = oz[0] + S * S;
        } else {                           // hashed levels, params = 2^21
            ox[0] = ix;                    ox[1] = ix + 1u;
            oy[0] = iy * 2654435761u;      oy[1] = oy[0] + 2654435761u;
            oz[0] = iz * 805459861u;       oz[1] = oz[0] + 805459861u;
        }

        float ax = 0.f, ay = 0.f, az = 0.f, aw = 0.f;
        #pragma unroll
        for (int c = 0; c < 8; ++c) {
            const int bx = (c >> 2) & 1, by = (c >> 1) & 1, bz = c & 1;
            unsigned idx;
            if (l < 3) idx = ox[bx] + oy[by] + oz[bz];
            else       idx = (ox[bx] ^ oy[by] ^ oz[bz]) & 0x1FFFFFu;
            const float w = wx[bx] * wy[by] * wz[bz];
            const float4 e = etab[OFF[l] + (int)idx];
            ax += w * e.x; ay += w * e.y; az += w * e.z; aw += w * e.w;
        }
        atomicAdd(&fsum[ray_l][l * 4 + 0], ax * wl);
        atomicAdd(&fsum[ray_l][l * 4 + 1], ay * wl);
        atomicAdd(&fsum[ray_l][l * 4 + 2], az * wl);
        atomicAdd(&fsum[ray_l][l * 4 + 3], aw * wl);
    }
}

// ---------------------------------------------------------------------------
// Kernel A: contraction + hash-grid encode + erf-weighted mean over samples.
// Block = 768 threads (12 waves) = 384 points x 2 level-halves (64 rays).
// Wave pair (wv>>1) covers 64 consecutive points; half = wv&1 picks levels.
// ---------------------------------------------------------------------------
__global__ __launch_bounds__(768) void enc_kernel(
    const float* __restrict__ means, const float* __restrict__ stds,
    const float* __restrict__ emb, float* __restrict__ features)
{
    __shared__ float fsum[64][40];
    const int tid  = threadIdx.x;
    const int lane = tid & 63;
    const int wv   = tid >> 6;            // 0..11
    const int half = wv & 1;              // 0: levels 0-4, 1: levels 5-9
    const int pidx = (wv >> 1) * 64 + lane;      // 0..383 point within block
    const int ray_l = pidx / 6;
    const int p    = blockIdx.x * 384 + pidx;    // global point

    for (int i = tid; i < 64 * 40; i += 768) (&fsum[0][0])[i] = 0.0f;
    __syncthreads();

    const float mx = means[p * 3 + 0], my = means[p * 3 + 1], mz = means[p * 3 + 2];
    const float sd = stds[p];

    // mipnerf360 contraction + std scaling
    float r2 = fmaxf(mx * mx + my * my + mz * mz, 1.1920929e-07f);
    float rr = sqrtf(r2);
    float zx, zy, zz, s;
    if (r2 <= 1.0f) { zx = mx; zy = my; zz = mz; s = sd; }
    else {
        float sc = (2.0f * rr - 1.0f) / r2;
        zx = mx * sc; zy = my * sc; zz = mz * sc;
        float det = (1.0f / r2) * sc * sc;
        s = sd * cbrtf(det);
    }
    zx *= 0.5f; zy *= 0.5f; zz *= 0.5f; s *= 0.5f;   // bound = 2
    const float ux = fminf(fmaxf((zx + 1.0f) * 0.5f, 0.0f), 1.0f);
    const float uy = fminf(fmaxf((zy + 1.0f) * 0.5f, 0.0f), 1.0f);
    const float uz = fminf(fmaxf((zz + 1.0f) * 0.5f, 0.0f), 1.0f);

    const float4* __restrict__ etab = (const float4*)emb;
    if (half == 0) encode5<0>(ux, uy, uz, s, etab, fsum, ray_l);
    else           encode5<5>(ux, uy, uz, s, etab, fsum, ray_l);
    __syncthreads();

    const float inv6 = 1.0f / 6.0f;
    for (int i = tid; i < 64 * 40; i += 768)
        features[blockIdx.x * 64 * 40 + i] = (&fsum[0][0])[i] * inv6;
}

// ---------------------------------------------------------------------------
// Kernel B: density MLP  features[64,40] -> h0[64] -> x[256] (bf16 out)
// ---------------------------------------------------------------------------
__global__ __launch_bounds__(256) void dens_kernel(
    const float* __restrict__ features,
    const float* __restrict__ dw0, const float* __restrict__ db0,
    const float* __restrict__ dw1, const float* __restrict__ db1,
    short* __restrict__ x_out, float* __restrict__ dens_out)
{
    __shared__ __align__(16) float feat_s[64][40];
    __shared__ __align__(16) float h0_s[64][64];
    const int tid  = threadIdx.x;
    const int ray0 = blockIdx.x * 64;

    for (int i = tid; i < 64 * 40; i += 256)
        (&feat_s[0][0])[i] = features[ray0 * 40 + i];
    __syncthreads();

    {   // layer 0: 40 -> 64, relu
        const int nn = tid & 63;
        const int q  = tid >> 6;
        float wk[40];
        #pragma unroll
        for (int k = 0; k < 40; ++k) wk[k] = dw0[k * 64 + nn];
        const float b = db0[nn];
        #pragma unroll 2
        for (int r = q * 16; r < q * 16 + 16; ++r) {
            float acc = b;
            #pragma unroll
            for (int k = 0; k < 40; ++k) acc += wk[k] * feat_s[r][k];
            h0_s[r][nn] = fmaxf(acc, 0.0f);
        }
    }
    __syncthreads();

    {   // layer 1: 64 -> 256; density = softplus(x0 - 1)
        const int nn = tid;
        float wk[64];
        #pragma unroll
        for (int k = 0; k < 64; ++k) wk[k] = dw1[k * 256 + nn];
        const float b = db1[nn];
        #pragma unroll 2
        for (int r = 0; r < 64; ++r) {
            float acc = b;
            #pragma unroll
            for (int k = 0; k < 64; ++k) acc += wk[k] * h0_s[r][k];
            x_out[(size_t)(ray0 + r) * 256 + nn] = f2bf(acc);
            if (nn == 0) {
                float z = acc - 1.0f;
                dens_out[ray0 + r] = fmaxf(z, 0.0f) + log1pf(expf(-fabsf(z)));
            }
        }
    }
}

// ---------------------------------------------------------------------------
// Kernel C: rgb branch via MFMA. 64 rays/block, 4 waves, wave = 16-ray m-tile.
// LDS row layout (bf16, stride 552): [y1(0..255) | x(256..511) | dir(512..538) | 0]
// ---------------------------------------------------------------------------
__global__ __launch_bounds__(256, 2) void rgb_mfma(
    const short* __restrict__ x_bf, const float* __restrict__ viewdirs,
    const short* __restrict__ w0p, const float* __restrict__ sb0,
    const short* __restrict__ w1p, const float* __restrict__ sb1,
    const float* __restrict__ rw,  const float* __restrict__ rb,
    float* __restrict__ out)
{
    __shared__ __align__(16) short inp_s[64][552];
    const int tid  = threadIdx.x;
    const int lane = tid & 63;
    const int wv   = tid >> 6;              // wave id = m-tile
    const int ray0 = blockIdx.x * 64;

    {   // x part -> cols 256..511 (short8 copies)
        const short8v* xg = (const short8v*)x_bf;
        for (int i = tid; i < 64 * 32; i += 256) {
            int r = i >> 5, c = i & 31;
            *(short8v*)&inp_s[r][256 + c * 8] = xg[(size_t)(ray0 + r) * 32 + c];
        }
    }
    for (int i = tid; i < 64 * 27; i += 256) {   // dir enc -> cols 512..538
        int r = i / 27, q = i % 27;
        const float* vd = &viewdirs[(size_t)(ray0 + r) * 3];
        float v;
        if (q < 3)       v = vd[q];
        else if (q < 15) { int ii = q - 3;  v = sinf(vd[ii % 3] * (float)(1 << (ii / 3))); }
        else             { int ii = q - 15; v = cosf(vd[ii % 3] * (float)(1 << (ii / 3))); }
        inp_s[r][512 + q] = f2bf(v);
    }
    for (int i = tid; i < 64 * 13; i += 256) {   // zero pad cols 539..551
        int r = i / 13, c = i % 13;
        inp_s[r][539 + c] = 0;
    }
    __syncthreads();

    const int arow  = wv * 16 + (lane & 15);
    const int kseg  = (lane >> 4) * 8;
    const int crow0 = wv * 16 + (lane >> 4) * 4;
    const int ccol  = lane & 15;
    const short8v* w0f = (const short8v*)w0p;
    const short8v* w1f = (const short8v*)w1p;

    float4v acc[16];

    // ---- GEMM1: y1 = relu(inp @ sw0 + sb0), K = 288 (9 k-steps)
    #pragma unroll
    for (int nt = 0; nt < 16; ++nt) acc[nt] = (float4v){0.f, 0.f, 0.f, 0.f};
    for (int ks = 0; ks < 9; ++ks) {
        short8v a = *(const short8v*)&inp_s[arow][256 + ks * 32 + kseg];
        #pragma unroll
        for (int nt = 0; nt < 16; ++nt) {
            short8v b = w0f[(ks * 16 + nt) * 64 + lane];
            acc[nt] = __builtin_amdgcn_mfma_f32_16x16x32_bf16(a, b, acc[nt], 0, 0, 0);
        }
    }
    #pragma unroll
    for (int nt = 0; nt < 16; ++nt) {
        float bias = sb0[nt * 16 + ccol];
        #pragma unroll
        for (int j = 0; j < 4; ++j)
            inp_s[crow0 + j][nt * 16 + ccol] = f2bf(fmaxf(acc[nt][j] + bias, 0.0f));
    }
    __syncthreads();

    // ---- GEMM2: y2 = relu([y1,x,dir] @ sw1 + sb1), K = 544 (17 k-steps)
    #pragma unroll
    for (int nt = 0; nt < 16; ++nt) acc[nt] = (float4v){0.f, 0.f, 0.f, 0.f};
    for (int ks = 0; ks < 17; ++ks) {
        short8v a = *(const short8v*)&inp_s[arow][ks * 32 + kseg];
        #pragma unroll
        for (int nt = 0; nt < 16; ++nt) {
            short8v b = w1f[(ks * 16 + nt) * 64 + lane];
            acc[nt] = __builtin_amdgcn_mfma_f32_16x16x32_bf16(a, b, acc[nt], 0, 0, 0);
        }
    }

    // ---- y2 = relu(acc + sb1) in regs; rgb = sigmoid(y2 @ rw + rb)
    float p[4][3];
    #pragma unroll
    for (int j = 0; j < 4; ++j) { p[j][0] = p[j][1] = p[j][2] = 0.f; }
    #pragma unroll
    for (int nt = 0; nt < 16; ++nt) {
        float bias = sb1[nt * 16 + ccol];
        const float* rwn = &rw[(size_t)(nt * 16 + ccol) * 3];
        float r0 = rwn[0], r1 = rwn[1], r2 = rwn[2];
        #pragma unroll
        for (int j = 0; j < 4; ++j) {
            float y = fmaxf(acc[nt][j] + bias, 0.0f);
            p[j][0] += y * r0; p[j][1] += y * r1; p[j][2] += y * r2;
        }
    }
    #pragma unroll
    for (int m = 1; m <= 8; m <<= 1) {
        #pragma unroll
        for (int j = 0; j < 4; ++j) {
            p[j][0] += __shfl_xor(p[j][0], m);
            p[j][1] += __shfl_xor(p[j][1], m);
            p[j][2] += __shfl_xor(p[j][2], m);
        }
    }
    if ((lane & 15) == 0) {
        #pragma unroll
        for (int j = 0; j < 4; ++j) {
            int ray = ray0 + crow0 + j;
            out[NRAYS + ray * 3 + 0] = sigmoidf_(p[j][0] + rb[0]) * 1.002f - 0.001f;
            out[NRAYS + ray * 3 + 1] = sigmoidf_(p[j][1] + rb[1]) * 1.002f - 0.001f;
            out[NRAYS + ray * 3 + 2] = sigmoidf_(p[j][2] + rb[2]) * 1.002f - 0.001f;
        }
    }
}

// ---------------------------------------------------------------------------
extern "C" void kernel_launch(void* const* d_in, const int* in_sizes, int n_in,
                              void* d_out, int out_size, void* d_ws, size_t ws_size,
                              hipStream_t stream)
{
    const float* means    = (const float*)d_in[0];
    const float* stds     = (const float*)d_in[1];
    const float* viewdirs = (const float*)d_in[2];
    const float* emb      = (const float*)d_in[3];
    const float* dw0      = (const float*)d_in[4];
    const float* db0      = (const float*)d_in[5];
    const float* dw1      = (const float*)d_in[6];
    const float* db1      = (const float*)d_in[7];
    const float* sw0      = (const float*)d_in[8];
    const float* sb0      = (const float*)d_in[9];
    const float* sw1      = (const float*)d_in[10];
    const float* sb1      = (const float*)d_in[11];
    const float* rw       = (const float*)d_in[12];
    const float* rb       = (const float*)d_in[13];

    float* out      = (float*)d_out;
    float* ws       = (float*)d_ws;
    float* features = ws;                                   // 32768*40 f32
    short* x_bf     = (short*)(ws + (size_t)NRAYS * 40);    // 32768*256 bf16
    short* w0p      = x_bf + (size_t)NRAYS * 256;           // 9*16*64*8
    short* w1p      = w0p + 9 * 16 * 64 * 8;                // 17*16*64*8

    pack_w<<<(9 * 16 * 64 * 8 + 255) / 256, 256, 0, stream>>>(sw0, w0p, 283, 9 * 16 * 64 * 8);
    pack_w<<<(17 * 16 * 64 * 8 + 255) / 256, 256, 0, stream>>>(sw1, w1p, 539, 17 * 16 * 64 * 8);
    enc_kernel <<<NRAYS / 64, 768, 0, stream>>>(means, stds, emb, features);
    dens_kernel<<<NRAYS / 64, 256, 0, stream>>>(features, dw0, db0, dw1, db1, x_bf, out);
    rgb_mfma   <<<NRAYS / 64, 256, 0, stream>>>(x_bf, viewdirs, w0p, sb0, w1p, sb1, rw, rb, out);
}